// Round 8
// baseline (365.765 us; speedup 1.0000x reference)
//
#include <hip/hip_runtime.h>
#include <hip/hip_fp16.h>
#include <math.h>

#define TT 2048
#define CC 64
#define BB 32
#define PAD 512
#define ROWL 3136          // padded bf16 row length

typedef __attribute__((ext_vector_type(8))) short short8;
typedef __attribute__((ext_vector_type(4))) float float4v;

// Toeplitz A-fragment tables: 67 K-steps x 64 lanes x 8 bf16 (hi/lo split)
#define NSTEPS 67
__device__ unsigned short g_afrag_hi[NSTEPS * 64 * 8];
__device__ unsigned short g_afrag_lo[NSTEPS * 64 * 8];

__device__ __forceinline__ float fast_rcp(float x) { return __builtin_amdgcn_rcpf(x); }
__device__ __forceinline__ float fast_exp2(float x) { return __builtin_amdgcn_exp2f(x); }
__device__ __forceinline__ float fast_log2(float x) { return __builtin_amdgcn_logf(x); }

__device__ __forceinline__ unsigned short f2bf(float x) {  // RNE bf16 round
  union { float f; unsigned u; } v; v.f = x;
  unsigned r = (v.u + 0x7FFFu + ((v.u >> 16) & 1u)) >> 16;
  return (unsigned short)r;
}
__device__ __forceinline__ float bf2f(unsigned short u) {
  union { unsigned u32; float f; } v; v.u32 = ((unsigned)u) << 16; return v.f;
}

// tanh-form GELU via sigmoid: x*sigma(1.595769x + 0.0713548x^3), max err ~4e-4
// exp(-s) = exp2(x*(-2.3020231 - 0.10294217*x^2))
__device__ __forceinline__ float gelu_f(float x) {
  float u = x * x;
  float w = x * fmaf(-0.10294217f, u, -2.3020231f);
  float e = fast_exp2(w);
  return x * fast_rcp(1.0f + e);
}

// ---- init: Gaussian taps -> Toeplitz MFMA fragments (grid-strided) ----
__global__ void init_frag() {
  __shared__ float ktap[2016];
  __shared__ double ssum[5];
  const int   Rr[5]  = {32, 64, 128, 256, 512};
  const float sg[5]  = {8.f, 16.f, 32.f, 64.f, 128.f};
  const int   off[5] = {0, 72, 208, 472, 984};
  const int tid = threadIdx.x;

  for (int idx = tid; idx < 2016; idx += 256) {
    int s = (idx < 72) ? 0 : (idx < 208) ? 1 : (idx < 472) ? 2 : (idx < 984) ? 3 : 4;
    int d = idx - off[s];
    float v = 0.f;
    if (d <= 2 * Rr[s]) {
      float n = (float)(d - Rr[s]) / sg[s];
      v = __expf(-0.5f * n * n);
    }
    ktap[idx] = v;
  }
  __syncthreads();
  if (tid < 5) {
    double sum = 0.0;
    for (int d = 0; d <= 2 * Rr[tid]; ++d) sum += (double)ktap[off[tid] + d];
    ssum[tid] = 1.0 / (sum + 1e-12);
  }
  __syncthreads();
  for (int idx = tid; idx < 2016; idx += 256) {
    int s = (idx < 72) ? 0 : (idx < 208) ? 1 : (idx < 472) ? 2 : (idx < 984) ? 3 : 4;
    ktap[idx] *= (float)ssum[s];
  }
  __syncthreads();

  const int cum[5] = {0, 3, 8, 17, 34};
  for (int e = blockIdx.x * 256 + tid; e < NSTEPS * 64; e += gridDim.x * 256) {
    int stg = e >> 6, lane = e & 63;
    int s = (stg < 3) ? 0 : (stg < 8) ? 1 : (stg < 17) ? 2 : (stg < 34) ? 3 : 4;
    int st = stg - cum[s];
    int i = lane & 15, h = lane >> 4;
    for (int e2 = 0; e2 < 8; ++e2) {
      int d = st * 32 + 8 * h + e2 - i;
      float v = (d >= 0 && d <= 2 * Rr[s]) ? ktap[off[s] + d] : 0.f;
      unsigned short hi = f2bf(v);
      g_afrag_hi[e * 8 + e2] = hi;
      g_afrag_lo[e * 8 + e2] = f2bf(v - bf2f(hi));
    }
  }
}

__launch_bounds__(256, 5)
__global__ void fused_main(const float* __restrict__ x,
                           const float* __restrict__ W1, const float* __restrict__ b1,
                           const float* __restrict__ W2, const float* __restrict__ b2,
                           const float* __restrict__ W3, const float* __restrict__ b3,
                           float* __restrict__ out) {
  __shared__ unsigned short row_hi[ROWL];
  __shared__ __half gbuf[8][5][16][18];   // gates; s=0..2 aliased as feats A1->A2

  const int tid = threadIdx.x;
  const int blk = blockIdx.x;            // NO swizzle (R7 post-mortem: swizzle 6.4x'd FETCH)
  const int c = blk & (CC - 1);
  const int b = blk >> 6;
  const float* xrow = x + (size_t)b * TT * CC + c;

  // ---- stage reflect-padded row as bf16 ----
  for (int i2 = tid; i2 < ROWL; i2 += 256) {
    int t = i2 - PAD;
    t = (t < 0) ? -t : t;
    t = (t >= TT) ? (2 * TT - 2 - t) : t;
    row_hi[i2] = f2bf(xrow[(size_t)t * CC]);
  }
  __syncthreads();

  const int t0 = tid * 8;
  const int lane = tid & 63;
  const int wvi = tid >> 6;

  // ======== Phase A1: sliding-window stats (bf16 x) -> feats ========
  {
    float w24[24];
    {
      const unsigned short* ph = &row_hi[PAD + t0 - 8];
      unsigned hw[12];
      *(uint4*)&hw[0] = *(const uint4*)ph;
      *(uint4*)&hw[4] = *(const uint4*)(ph + 8);
      *(uint4*)&hw[8] = *(const uint4*)(ph + 16);
      #pragma unroll
      for (int m2 = 0; m2 < 12; ++m2) {
        union { unsigned u; float f; } a, bb;
        a.u  = (hw[m2] & 0xFFFFu) << 16;
        bb.u = hw[m2] & 0xFFFF0000u;
        w24[2 * m2]     = a.f;
        w24[2 * m2 + 1] = bb.f;
      }
    }

    float sm = 0.f, sq = 0.f, scv = 0.f;
    #pragma unroll
    for (int j = 0; j < 16; ++j) {
      float v = w24[1 + j];
      sm += v;
      sq  = fmaf(v, v, sq);
      scv = fmaf(v, (float)j - 7.5f, scv);
    }

    #pragma unroll
    for (int i = 0; i < 8; ++i) {
      const float xv   = w24[i + 8];
      const float mean = sm * 0.0625f;
      const float ex2  = sq * 0.0625f;
      const float var  = fmaxf(ex2 - mean * mean, 0.f);
      const float slope = scv * (1.0f / 340.0f);
      const float stdv = sqrtf(var + 1e-6f);
      float z = (xv - mean) * fast_rcp(stdv);
      z = fminf(fmaxf(z, -10.f), 10.f);
      float lv = fast_log2(var + 1e-6f) * 0.069314718f;   // *ln2/10 = ln(.)/10
      float ns = slope * fast_rcp(stdv + 1e-6f);
      ns = fminf(fmaxf(ns, -10.f), 10.f);

      const int e = t0 + i;
      const int ch = e >> 8, rr = e & 15, pp = (e >> 4) & 15;
      gbuf[ch][0][rr][pp] = __float2half(z);
      gbuf[ch][1][rr][pp] = __float2half(lv);
      gbuf[ch][2][rr][pp] = __float2half(ns);

      if (i < 7) {   // slide window by one
        const float xo = w24[i + 1], xn = w24[i + 17];
        scv = fmaf(8.5f, xo, fmaf(7.5f, xn, scv - sm));
        sm += (xn - xo);
        sq = fmaf(xn, xn, sq);
        sq = fmaf(-xo, xo, sq);
      }
    }
  }

  // ======== Phase A2: wave-wide MLP via MFMA ========
  {
    const int kg = lane >> 4;        // k-group == row-quarter hq
    const int m  = lane & 15;        // element column

    // W2 A-fragments (hi/lo) built in-register from global W2
    short8 w2h0, w2l0, w2h1, w2l1;
    {
      const float* p0 = W2 + (size_t)m * 32 + 8 * kg;
      const float* p1 = W2 + (size_t)(16 + m) * 32 + 8 * kg;
      #pragma unroll
      for (int e2 = 0; e2 < 8; ++e2) {
        float v0 = p0[e2], v1 = p1[e2];
        unsigned short h0 = f2bf(v0);
        w2h0[e2] = (short)h0; w2l0[e2] = (short)f2bf(v0 - bf2f(h0));
        unsigned short h1v = f2bf(v1);
        w2h1[e2] = (short)h1v; w2l1[e2] = (short)f2bf(v1 - bf2f(h1v));
      }
    }

    float4v w1q[6], b1q2[2], b2a, b2b, w3A[5], w3B[5];
    #pragma unroll
    for (int k = 0; k < 6; ++k) w1q[k] = *(const float4v*)(W1 + 24 * kg + 4 * k);
    b1q2[0] = *(const float4v*)(b1 + 8 * kg);
    b1q2[1] = *(const float4v*)(b1 + 8 * kg + 4);
    b2a = *(const float4v*)(b2 + 4 * kg);
    b2b = *(const float4v*)(b2 + 16 + 4 * kg);
    #pragma unroll
    for (int k = 0; k < 5; ++k) {
      w3A[k] = *(const float4v*)(W3 + 32 * k + 4 * kg);
      w3B[k] = *(const float4v*)(W3 + 32 * k + 16 + 4 * kg);
    }
    const float b30 = b3[0], b31 = b3[1], b32 = b3[2], b33 = b3[3], b34 = b3[4];
    const float kS = 2.0609929f;     // log2(e)/0.7

    #pragma unroll 1
    for (int j = 0; j < 32; ++j) {
      const int ch = 2 * wvi + (j >> 4);
      const int pp = j & 15;

      // features of column element m
      float z  = __half2float(gbuf[ch][0][m][pp]);
      float lv = __half2float(gbuf[ch][1][m][pp]);
      float ns = __half2float(gbuf[ch][2][m][pp]);

      // layer 1 in B-fragment layout: 8 neurons (k = 8*kg + e2) of column m
      short8 bfr;
      #pragma unroll
      for (int e2 = 0; e2 < 8; ++e2) {
        float p = b1q2[e2 >> 2][e2 & 3];
        p = fmaf(w1q[(3*e2)   >> 2][(3*e2)   & 3], z,  p);
        p = fmaf(w1q[(3*e2+1) >> 2][(3*e2+1) & 3], lv, p);
        p = fmaf(w1q[(3*e2+2) >> 2][(3*e2+2) & 3], ns, p);
        bfr[e2] = (short)f2bf(gelu_f(p));
      }

      // layer 2: h2pre = W2 * h1  (2 g-tiles, W2 hi/lo 2-pass)
      float4v acc0 = {0.f,0.f,0.f,0.f}, acc1 = {0.f,0.f,0.f,0.f};
      acc0 = __builtin_amdgcn_mfma_f32_16x16x32_bf16(w2h0, bfr, acc0, 0, 0, 0);
      acc0 = __builtin_amdgcn_mfma_f32_16x16x32_bf16(w2l0, bfr, acc0, 0, 0, 0);
      acc1 = __builtin_amdgcn_mfma_f32_16x16x32_bf16(w2h1, bfr, acc1, 0, 0, 0);
      acc1 = __builtin_amdgcn_mfma_f32_16x16x32_bf16(w2l1, bfr, acc1, 0, 0, 0);

      // bias + GELU + W3 partial dot (rows g = 16gt + 4kg + r)
      float lg0 = 0.f, lg1 = 0.f, lg2 = 0.f, lg3 = 0.f, lg4 = 0.f;
      #pragma unroll
      for (int r = 0; r < 4; ++r) {
        float ha = gelu_f(acc0[r] + b2a[r]);
        float hb = gelu_f(acc1[r] + b2b[r]);
        lg0 = fmaf(w3A[0][r], ha, lg0); lg0 = fmaf(w3B[0][r], hb, lg0);
        lg1 = fmaf(w3A[1][r], ha, lg1); lg1 = fmaf(w3B[1][r], hb, lg1);
        lg2 = fmaf(w3A[2][r], ha, lg2); lg2 = fmaf(w3B[2][r], hb, lg2);
        lg3 = fmaf(w3A[3][r], ha, lg3); lg3 = fmaf(w3B[3][r], hb, lg3);
        lg4 = fmaf(w3A[4][r], ha, lg4); lg4 = fmaf(w3B[4][r], hb, lg4);
      }
      // reduce across the 4 row-quarters (lanes m, m+16, m+32, m+48)
      lg0 += __shfl_xor(lg0, 16); lg0 += __shfl_xor(lg0, 32);
      lg1 += __shfl_xor(lg1, 16); lg1 += __shfl_xor(lg1, 32);
      lg2 += __shfl_xor(lg2, 16); lg2 += __shfl_xor(lg2, 32);
      lg3 += __shfl_xor(lg3, 16); lg3 += __shfl_xor(lg3, 32);
      lg4 += __shfl_xor(lg4, 16); lg4 += __shfl_xor(lg4, 32);
      lg0 += b30; lg1 += b31; lg2 += b32; lg3 += b33; lg4 += b34;

      // softmax(logits/0.7) via exp2 with folded scale
      const float mx = fmaxf(fmaxf(fmaxf(lg0, lg1), fmaxf(lg2, lg3)), lg4);
      const float mxs = mx * kS;
      float e0 = fast_exp2(fmaf(lg0, kS, -mxs));
      float e1 = fast_exp2(fmaf(lg1, kS, -mxs));
      float e2 = fast_exp2(fmaf(lg2, kS, -mxs));
      float e3 = fast_exp2(fmaf(lg3, kS, -mxs));
      float e4 = fast_exp2(fmaf(lg4, kS, -mxs));
      const float rs = fast_rcp(e0 + e1 + e2 + e3 + e4);

      // each quarter writes its own scale slot; quarter 0 also writes s=4
      float gw = e0;
      gw = (kg == 1) ? e1 : gw;
      gw = (kg == 2) ? e2 : gw;
      gw = (kg == 3) ? e3 : gw;
      gbuf[ch][kg][m][pp] = __float2half(gw * rs);
      if (kg == 0) gbuf[ch][4][m][pp] = __float2half(e4 * rs);
    }
  }
  // gates produced & consumed by the same wave -> no barrier needed

  // ======== Phase B: Toeplitz-MFMA conv (tap hi/lo, single bf16 B) ========
  {
    const int hq = lane >> 4, p = lane & 15;
    const int ch0 = 2 * wvi, ch1 = 2 * wvi + 1;

    const int Rs[5]    = {32, 64, 128, 256, 512};
    const int steps[5] = {3, 5, 9, 17, 33};
    const int cum[5]   = {0, 3, 8, 17, 34};

    float4v o0 = {0.f,0.f,0.f,0.f}, o1 = {0.f,0.f,0.f,0.f};

    #pragma unroll 1
    for (int s = 0; s < 5; ++s) {
      float4v a0 = {0.f,0.f,0.f,0.f}, a1 = {0.f,0.f,0.f,0.f};
      const int eb0 = PAD + 256 * ch0 - Rs[s] + 16 * p + 8 * hq;
      const int eb1 = eb0 + 256;
      const unsigned short* ahb = g_afrag_hi + (size_t)cum[s] * 512 + lane * 8;
      const unsigned short* alb = g_afrag_lo + (size_t)cum[s] * 512 + lane * 8;

      for (int st = 0; st < steps[s]; ++st) {
        short8 kh = *(const short8*)(ahb + st * 512);
        short8 kl = *(const short8*)(alb + st * 512);
        short8 b0h = *(const short8*)(&row_hi[eb0 + st * 32]);
        short8 b1h = *(const short8*)(&row_hi[eb1 + st * 32]);
        a0 = __builtin_amdgcn_mfma_f32_16x16x32_bf16(kh, b0h, a0, 0, 0, 0);
        a0 = __builtin_amdgcn_mfma_f32_16x16x32_bf16(kl, b0h, a0, 0, 0, 0);
        a1 = __builtin_amdgcn_mfma_f32_16x16x32_bf16(kh, b1h, a1, 0, 0, 0);
        a1 = __builtin_amdgcn_mfma_f32_16x16x32_bf16(kl, b1h, a1, 0, 0, 0);
      }
      #pragma unroll
      for (int r = 0; r < 4; ++r) {
        o0[r] = fmaf(__half2float(gbuf[ch0][s][4 * hq + r][p]), a0[r], o0[r]);
        o1[r] = fmaf(__half2float(gbuf[ch1][s][4 * hq + r][p]), a1[r], o1[r]);
      }
    }

    const size_t obase = (size_t)b * TT * CC + c;
    #pragma unroll
    for (int r = 0; r < 4; ++r) {
      out[obase + (size_t)(256 * ch0 + 16 * p + 4 * hq + r) * CC] = o0[r];
      out[obase + (size_t)(256 * ch1 + 16 * p + 4 * hq + r) * CC] = o1[r];
    }
  }
}

extern "C" void kernel_launch(void* const* d_in, const int* in_sizes, int n_in,
                              void* d_out, int out_size, void* d_ws, size_t ws_size,
                              hipStream_t stream) {
  const float* x  = (const float*)d_in[0];
  const float* W1 = (const float*)d_in[1];
  const float* b1 = (const float*)d_in[2];
  const float* W2 = (const float*)d_in[3];
  const float* b2 = (const float*)d_in[4];
  const float* W3 = (const float*)d_in[5];
  const float* b3 = (const float*)d_in[6];
  float* outp = (float*)d_out;

  hipLaunchKernelGGL(init_frag, dim3(8), dim3(256), 0, stream);
  hipLaunchKernelGGL(fused_main, dim3(BB * CC), dim3(256), 0, stream,
                     x, W1, b1, W2, b2, W3, b3, outp);
}

// Round 9
// 346.677 us; speedup vs baseline: 1.0551x; 1.0551x over previous
//
#include <hip/hip_runtime.h>
#include <hip/hip_fp16.h>
#include <math.h>

#define TT 2048
#define CC 64
#define BB 32
#define PAD 512
#define ROWL 3136          // padded bf16 row length

typedef __attribute__((ext_vector_type(8))) short short8;
typedef __attribute__((ext_vector_type(4))) float float4v;

// Toeplitz A-fragment tables: 67 K-steps x 64 lanes x 8 bf16 (hi/lo split)
#define NSTEPS 67
__device__ unsigned short g_afrag_hi[NSTEPS * 64 * 8];
__device__ unsigned short g_afrag_lo[NSTEPS * 64 * 8];

__device__ __forceinline__ float fast_rcp(float x) { return __builtin_amdgcn_rcpf(x); }
__device__ __forceinline__ float fast_exp2(float x) { return __builtin_amdgcn_exp2f(x); }
__device__ __forceinline__ float fast_log2(float x) { return __builtin_amdgcn_logf(x); }

__device__ __forceinline__ unsigned short f2bf(float x) {  // RNE bf16 round
  union { float f; unsigned u; } v; v.f = x;
  unsigned r = (v.u + 0x7FFFu + ((v.u >> 16) & 1u)) >> 16;
  return (unsigned short)r;
}
__device__ __forceinline__ float bf2f(unsigned short u) {
  union { unsigned u32; float f; } v; v.u32 = ((unsigned)u) << 16; return v.f;
}

// tanh-form GELU via sigmoid: x*sigma(1.595769x + 0.0713548x^3), max err ~4e-4
__device__ __forceinline__ float gelu_f(float x) {
  float u = x * x;
  float w = x * fmaf(-0.10294217f, u, -2.3020231f);
  float e = fast_exp2(w);
  return x * fast_rcp(1.0f + e);
}

// ---- init: Gaussian taps -> Toeplitz MFMA fragments (grid-strided) ----
__global__ void init_frag() {
  __shared__ float ktap[2016];
  __shared__ double ssum[5];
  const int   Rr[5]  = {32, 64, 128, 256, 512};
  const float sg[5]  = {8.f, 16.f, 32.f, 64.f, 128.f};
  const int   off[5] = {0, 72, 208, 472, 984};
  const int tid = threadIdx.x;

  for (int idx = tid; idx < 2016; idx += 256) {
    int s = (idx < 72) ? 0 : (idx < 208) ? 1 : (idx < 472) ? 2 : (idx < 984) ? 3 : 4;
    int d = idx - off[s];
    float v = 0.f;
    if (d <= 2 * Rr[s]) {
      float n = (float)(d - Rr[s]) / sg[s];
      v = __expf(-0.5f * n * n);
    }
    ktap[idx] = v;
  }
  __syncthreads();
  if (tid < 5) {
    double sum = 0.0;
    for (int d = 0; d <= 2 * Rr[tid]; ++d) sum += (double)ktap[off[tid] + d];
    ssum[tid] = 1.0 / (sum + 1e-12);
  }
  __syncthreads();
  for (int idx = tid; idx < 2016; idx += 256) {
    int s = (idx < 72) ? 0 : (idx < 208) ? 1 : (idx < 472) ? 2 : (idx < 984) ? 3 : 4;
    ktap[idx] *= (float)ssum[s];
  }
  __syncthreads();

  const int cum[5] = {0, 3, 8, 17, 34};
  for (int e = blockIdx.x * 256 + tid; e < NSTEPS * 64; e += gridDim.x * 256) {
    int stg = e >> 6, lane = e & 63;
    int s = (stg < 3) ? 0 : (stg < 8) ? 1 : (stg < 17) ? 2 : (stg < 34) ? 3 : 4;
    int st = stg - cum[s];
    int i = lane & 15, h = lane >> 4;
    for (int e2 = 0; e2 < 8; ++e2) {
      int d = st * 32 + 8 * h + e2 - i;
      float v = (d >= 0 && d <= 2 * Rr[s]) ? ktap[off[s] + d] : 0.f;
      unsigned short hi = f2bf(v);
      g_afrag_hi[e * 8 + e2] = hi;
      g_afrag_lo[e * 8 + e2] = f2bf(v - bf2f(hi));
    }
  }
}

// ---- transpose x [B,T,C] fp32 -> xT [B,C,T] bf16 (coalesced both sides) ----
__global__ void transpose_in(const float* __restrict__ x, unsigned short* __restrict__ xT) {
  __shared__ float tile[64][65];
  const int tid = threadIdx.x;
  const int b = blockIdx.x >> 5;           // 32 t-tiles per batch
  const int t0 = (blockIdx.x & 31) * 64;

  const float* src = x + ((size_t)b * TT + t0) * CC;
  #pragma unroll
  for (int k = 0; k < 16; ++k) {
    int idx = k * 256 + tid;
    int row = idx >> 6, col = idx & 63;     // lanes: fixed row, col 0..63 -> 256B coalesced
    tile[row][col] = src[(size_t)row * CC + col];
  }
  __syncthreads();
  unsigned short* dst = xT + (size_t)b * CC * TT + t0;
  #pragma unroll
  for (int k = 0; k < 16; ++k) {
    int idx = k * 256 + tid;
    int c = idx >> 6, tt = idx & 63;        // lanes: fixed c, tt 0..63 -> 128B coalesced
    dst[(size_t)c * TT + tt] = f2bf(tile[tt][c]);
  }
}

template <int XTPATH>
__launch_bounds__(256, 5)
__global__ void fused_main_t(const float* __restrict__ x, const unsigned short* __restrict__ xT,
                             const float* __restrict__ W1, const float* __restrict__ b1,
                             const float* __restrict__ W2, const float* __restrict__ b2,
                             const float* __restrict__ W3, const float* __restrict__ b3,
                             float* __restrict__ out) {
  __shared__ unsigned short row_hi[ROWL];
  __shared__ __half gbuf[8][5][16][18];   // gates; s=0..2 aliased as feats A1->A2

  const int tid = threadIdx.x;
  const int blk = blockIdx.x;
  const int c = blk & (CC - 1);
  const int b = blk >> 6;

  // ---- stage reflect-padded row as bf16 ----
  if (XTPATH) {
    const unsigned short* xtr = xT + (size_t)(b * CC + c) * TT;   // contiguous bf16 row
    for (int i2 = tid; i2 < ROWL; i2 += 256) {
      int t = i2 - PAD;
      t = (t < 0) ? -t : t;
      t = (t >= TT) ? (2 * TT - 2 - t) : t;
      row_hi[i2] = xtr[t];
    }
  } else {
    const float* xrow = x + (size_t)b * TT * CC + c;
    for (int i2 = tid; i2 < ROWL; i2 += 256) {
      int t = i2 - PAD;
      t = (t < 0) ? -t : t;
      t = (t >= TT) ? (2 * TT - 2 - t) : t;
      row_hi[i2] = f2bf(xrow[(size_t)t * CC]);
    }
  }
  __syncthreads();

  const int t0 = tid * 8;
  const int lane = tid & 63;
  const int wvi = tid >> 6;

  // ======== Phase A1: sliding-window stats (bf16 x) -> feats ========
  {
    float w24[24];
    {
      const unsigned short* ph = &row_hi[PAD + t0 - 8];
      unsigned hw[12];
      *(uint4*)&hw[0] = *(const uint4*)ph;
      *(uint4*)&hw[4] = *(const uint4*)(ph + 8);
      *(uint4*)&hw[8] = *(const uint4*)(ph + 16);
      #pragma unroll
      for (int m2 = 0; m2 < 12; ++m2) {
        union { unsigned u; float f; } a, bb;
        a.u  = (hw[m2] & 0xFFFFu) << 16;
        bb.u = hw[m2] & 0xFFFF0000u;
        w24[2 * m2]     = a.f;
        w24[2 * m2 + 1] = bb.f;
      }
    }

    float sm = 0.f, sq = 0.f, scv = 0.f;
    #pragma unroll
    for (int j = 0; j < 16; ++j) {
      float v = w24[1 + j];
      sm += v;
      sq  = fmaf(v, v, sq);
      scv = fmaf(v, (float)j - 7.5f, scv);
    }

    #pragma unroll
    for (int i = 0; i < 8; ++i) {
      const float xv   = w24[i + 8];
      const float mean = sm * 0.0625f;
      const float ex2  = sq * 0.0625f;
      const float var  = fmaxf(ex2 - mean * mean, 0.f);
      const float slope = scv * (1.0f / 340.0f);
      const float stdv = sqrtf(var + 1e-6f);
      float z = (xv - mean) * fast_rcp(stdv);
      z = fminf(fmaxf(z, -10.f), 10.f);
      float lv = fast_log2(var + 1e-6f) * 0.069314718f;   // *ln2/10 = ln(.)/10
      float ns = slope * fast_rcp(stdv + 1e-6f);
      ns = fminf(fmaxf(ns, -10.f), 10.f);

      const int e = t0 + i;
      const int ch = e >> 8, rr = e & 15, pp = (e >> 4) & 15;
      gbuf[ch][0][rr][pp] = __float2half(z);
      gbuf[ch][1][rr][pp] = __float2half(lv);
      gbuf[ch][2][rr][pp] = __float2half(ns);

      if (i < 7) {   // slide window by one
        const float xo = w24[i + 1], xn = w24[i + 17];
        scv = fmaf(8.5f, xo, fmaf(7.5f, xn, scv - sm));
        sm += (xn - xo);
        sq = fmaf(xn, xn, sq);
        sq = fmaf(-xo, xo, sq);
      }
    }
  }

  // ======== Phase A2: wave-wide MLP via MFMA ========
  {
    const int kg = lane >> 4;        // k-group == row-quarter hq
    const int m  = lane & 15;        // element column

    // W2 A-fragments (hi/lo) built in-register from global W2
    short8 w2h0, w2l0, w2h1, w2l1;
    {
      const float* p0 = W2 + (size_t)m * 32 + 8 * kg;
      const float* p1 = W2 + (size_t)(16 + m) * 32 + 8 * kg;
      #pragma unroll
      for (int e2 = 0; e2 < 8; ++e2) {
        float v0 = p0[e2], v1 = p1[e2];
        unsigned short h0 = f2bf(v0);
        w2h0[e2] = (short)h0; w2l0[e2] = (short)f2bf(v0 - bf2f(h0));
        unsigned short h1v = f2bf(v1);
        w2h1[e2] = (short)h1v; w2l1[e2] = (short)f2bf(v1 - bf2f(h1v));
      }
    }

    float4v w1q[6], b1q2[2], b2a, b2b, w3A[5], w3B[5];
    #pragma unroll
    for (int k = 0; k < 6; ++k) w1q[k] = *(const float4v*)(W1 + 24 * kg + 4 * k);
    b1q2[0] = *(const float4v*)(b1 + 8 * kg);
    b1q2[1] = *(const float4v*)(b1 + 8 * kg + 4);
    b2a = *(const float4v*)(b2 + 4 * kg);
    b2b = *(const float4v*)(b2 + 16 + 4 * kg);
    #pragma unroll
    for (int k = 0; k < 5; ++k) {
      w3A[k] = *(const float4v*)(W3 + 32 * k + 4 * kg);
      w3B[k] = *(const float4v*)(W3 + 32 * k + 16 + 4 * kg);
    }
    const float b30 = b3[0], b31 = b3[1], b32 = b3[2], b33 = b3[3], b34 = b3[4];
    const float kS = 2.0609929f;     // log2(e)/0.7

    #pragma unroll 1
    for (int j = 0; j < 32; ++j) {
      const int ch = 2 * wvi + (j >> 4);
      const int pp = j & 15;

      // features of column element m
      float z  = __half2float(gbuf[ch][0][m][pp]);
      float lv = __half2float(gbuf[ch][1][m][pp]);
      float ns = __half2float(gbuf[ch][2][m][pp]);

      // layer 1 in B-fragment layout: 8 neurons (k = 8*kg + e2) of column m
      short8 bfr;
      #pragma unroll
      for (int e2 = 0; e2 < 8; ++e2) {
        float p = b1q2[e2 >> 2][e2 & 3];
        p = fmaf(w1q[(3*e2)   >> 2][(3*e2)   & 3], z,  p);
        p = fmaf(w1q[(3*e2+1) >> 2][(3*e2+1) & 3], lv, p);
        p = fmaf(w1q[(3*e2+2) >> 2][(3*e2+2) & 3], ns, p);
        bfr[e2] = (short)f2bf(gelu_f(p));
      }

      // layer 2: h2pre = W2 * h1  (2 g-tiles, W2 hi/lo 2-pass)
      float4v acc0 = {0.f,0.f,0.f,0.f}, acc1 = {0.f,0.f,0.f,0.f};
      acc0 = __builtin_amdgcn_mfma_f32_16x16x32_bf16(w2h0, bfr, acc0, 0, 0, 0);
      acc0 = __builtin_amdgcn_mfma_f32_16x16x32_bf16(w2l0, bfr, acc0, 0, 0, 0);
      acc1 = __builtin_amdgcn_mfma_f32_16x16x32_bf16(w2h1, bfr, acc1, 0, 0, 0);
      acc1 = __builtin_amdgcn_mfma_f32_16x16x32_bf16(w2l1, bfr, acc1, 0, 0, 0);

      // bias + GELU + W3 partial dot (rows g = 16gt + 4kg + r)
      float lg0 = 0.f, lg1 = 0.f, lg2 = 0.f, lg3 = 0.f, lg4 = 0.f;
      #pragma unroll
      for (int r = 0; r < 4; ++r) {
        float ha = gelu_f(acc0[r] + b2a[r]);
        float hb = gelu_f(acc1[r] + b2b[r]);
        lg0 = fmaf(w3A[0][r], ha, lg0); lg0 = fmaf(w3B[0][r], hb, lg0);
        lg1 = fmaf(w3A[1][r], ha, lg1); lg1 = fmaf(w3B[1][r], hb, lg1);
        lg2 = fmaf(w3A[2][r], ha, lg2); lg2 = fmaf(w3B[2][r], hb, lg2);
        lg3 = fmaf(w3A[3][r], ha, lg3); lg3 = fmaf(w3B[3][r], hb, lg3);
        lg4 = fmaf(w3A[4][r], ha, lg4); lg4 = fmaf(w3B[4][r], hb, lg4);
      }
      // reduce across the 4 row-quarters (lanes m, m+16, m+32, m+48)
      lg0 += __shfl_xor(lg0, 16); lg0 += __shfl_xor(lg0, 32);
      lg1 += __shfl_xor(lg1, 16); lg1 += __shfl_xor(lg1, 32);
      lg2 += __shfl_xor(lg2, 16); lg2 += __shfl_xor(lg2, 32);
      lg3 += __shfl_xor(lg3, 16); lg3 += __shfl_xor(lg3, 32);
      lg4 += __shfl_xor(lg4, 16); lg4 += __shfl_xor(lg4, 32);
      lg0 += b30; lg1 += b31; lg2 += b32; lg3 += b33; lg4 += b34;

      // softmax(logits/0.7) via exp2 with folded scale
      const float mx = fmaxf(fmaxf(fmaxf(lg0, lg1), fmaxf(lg2, lg3)), lg4);
      const float mxs = mx * kS;
      float e0 = fast_exp2(fmaf(lg0, kS, -mxs));
      float e1 = fast_exp2(fmaf(lg1, kS, -mxs));
      float e2 = fast_exp2(fmaf(lg2, kS, -mxs));
      float e3 = fast_exp2(fmaf(lg3, kS, -mxs));
      float e4 = fast_exp2(fmaf(lg4, kS, -mxs));
      const float rs = fast_rcp(e0 + e1 + e2 + e3 + e4);

      // each quarter writes its own scale slot; quarter 0 also writes s=4
      float gw = e0;
      gw = (kg == 1) ? e1 : gw;
      gw = (kg == 2) ? e2 : gw;
      gw = (kg == 3) ? e3 : gw;
      gbuf[ch][kg][m][pp] = __float2half(gw * rs);
      if (kg == 0) gbuf[ch][4][m][pp] = __float2half(e4 * rs);
    }
  }
  // gates produced & consumed by the same wave -> no barrier needed

  // ======== Phase B: Toeplitz-MFMA conv (tap hi/lo, single bf16 B) ========
  {
    const int hq = lane >> 4, p = lane & 15;
    const int ch0 = 2 * wvi, ch1 = 2 * wvi + 1;

    const int Rs[5]    = {32, 64, 128, 256, 512};
    const int steps[5] = {3, 5, 9, 17, 33};
    const int cum[5]   = {0, 3, 8, 17, 34};

    float4v o0 = {0.f,0.f,0.f,0.f}, o1 = {0.f,0.f,0.f,0.f};

    #pragma unroll 1
    for (int s = 0; s < 5; ++s) {
      float4v a0 = {0.f,0.f,0.f,0.f}, a1 = {0.f,0.f,0.f,0.f};
      const int eb0 = PAD + 256 * ch0 - Rs[s] + 16 * p + 8 * hq;
      const int eb1 = eb0 + 256;
      const unsigned short* ahb = g_afrag_hi + (size_t)cum[s] * 512 + lane * 8;
      const unsigned short* alb = g_afrag_lo + (size_t)cum[s] * 512 + lane * 8;

      for (int st = 0; st < steps[s]; ++st) {
        short8 kh = *(const short8*)(ahb + st * 512);
        short8 kl = *(const short8*)(alb + st * 512);
        short8 b0h = *(const short8*)(&row_hi[eb0 + st * 32]);
        short8 b1h = *(const short8*)(&row_hi[eb1 + st * 32]);
        a0 = __builtin_amdgcn_mfma_f32_16x16x32_bf16(kh, b0h, a0, 0, 0, 0);
        a0 = __builtin_amdgcn_mfma_f32_16x16x32_bf16(kl, b0h, a0, 0, 0, 0);
        a1 = __builtin_amdgcn_mfma_f32_16x16x32_bf16(kh, b1h, a1, 0, 0, 0);
        a1 = __builtin_amdgcn_mfma_f32_16x16x32_bf16(kl, b1h, a1, 0, 0, 0);
      }
      #pragma unroll
      for (int r = 0; r < 4; ++r) {
        o0[r] = fmaf(__half2float(gbuf[ch0][s][4 * hq + r][p]), a0[r], o0[r]);
        o1[r] = fmaf(__half2float(gbuf[ch1][s][4 * hq + r][p]), a1[r], o1[r]);
      }
    }

    const size_t obase = (size_t)b * TT * CC + c;
    #pragma unroll
    for (int r = 0; r < 4; ++r) {
      out[obase + (size_t)(256 * ch0 + 16 * p + 4 * hq + r) * CC] = o0[r];
      out[obase + (size_t)(256 * ch1 + 16 * p + 4 * hq + r) * CC] = o1[r];
    }
  }
}

extern "C" void kernel_launch(void* const* d_in, const int* in_sizes, int n_in,
                              void* d_out, int out_size, void* d_ws, size_t ws_size,
                              hipStream_t stream) {
  const float* x  = (const float*)d_in[0];
  const float* W1 = (const float*)d_in[1];
  const float* b1 = (const float*)d_in[2];
  const float* W2 = (const float*)d_in[3];
  const float* b2 = (const float*)d_in[4];
  const float* W3 = (const float*)d_in[5];
  const float* b3 = (const float*)d_in[6];
  float* outp = (float*)d_out;

  hipLaunchKernelGGL(init_frag, dim3(8), dim3(256), 0, stream);

  const size_t xt_bytes = (size_t)BB * CC * TT * sizeof(unsigned short);  // 8.4 MB
  if (ws_size >= xt_bytes) {
    unsigned short* xT = (unsigned short*)d_ws;
    hipLaunchKernelGGL(transpose_in, dim3(BB * 32), dim3(256), 0, stream, x, xT);
    hipLaunchKernelGGL(fused_main_t<1>, dim3(BB * CC), dim3(256), 0, stream,
                       x, xT, W1, b1, W2, b2, W3, b3, outp);
  } else {
    hipLaunchKernelGGL(fused_main_t<0>, dim3(BB * CC), dim3(256), 0, stream,
                       x, (const unsigned short*)nullptr, W1, b1, W2, b2, W3, b3, outp);
  }
}